// Round 1
// baseline (288.851 us; speedup 1.0000x reference)
//
#include <hip/hip_runtime.h>
#include <hip/hip_bf16.h>
#include <stdint.h>

typedef __attribute__((ext_vector_type(8))) __bf16 bf16x8;
typedef __attribute__((ext_vector_type(4))) float floatx4;

#define EPS 1e-5f

__device__ __forceinline__ unsigned short f2bf(float f) {
    union { float f; unsigned int u; } x; x.f = f;
    unsigned int r = x.u + 0x7fffu + ((x.u >> 16) & 1u);
    return (unsigned short)(r >> 16);
}

// ---------------- weight transpose + fp32->bf16 convert ----------------
struct WDesc { const float* src; unsigned short* dst; int rows; int cols; };
struct WPack { WDesc w[8]; };

__global__ void conv_weights(WPack p) {
    WDesc d = p.w[blockIdx.y];
    int i = blockIdx.x * 256 + threadIdx.x;
    int tot = d.rows * d.cols;
    if (i >= tot) return;
    int r = i / d.cols;
    int c = i - r * d.cols;
    d.dst[(size_t)c * d.rows + r] = f2bf(d.src[i]);   // dst is [cols, rows] = B^T
}

__global__ void conv_x(const float* __restrict__ x, unsigned short* __restrict__ xb) {
    int i = blockIdx.x * 256 + threadIdx.x;
    const float4 v = ((const float4*)x)[i];
    ushort4 o;
    o.x = f2bf(v.x); o.y = f2bf(v.y); o.z = f2bf(v.z); o.w = f2bf(v.w);
    ((ushort4*)xb)[i] = o;
}

// ---------------- MFMA GEMM: C = A[M,K] * B[K,N]  (B given transposed [N,K]) ----
// 128x128 block tile, BK=64, 256 threads = 4 waves in 2x2, each wave 64x64
// LDS layout: 16B chunks (8 bf16 along k), chunk index = row*8 + (kq ^ (row&7))
__device__ __forceinline__ void stage_tile(const unsigned short* __restrict__ g,
                                           int ld, int row0, int k0,
                                           bf16x8* lds, int tid) {
#pragma unroll
    for (int i = 0; i < 4; ++i) {
        int c  = i * 256 + tid;
        int r  = c >> 3;      // 0..127 local row
        int kq = c & 7;       // 16B chunk within 64-wide k tile
        bf16x8 v = *(const bf16x8*)(g + (size_t)(row0 + r) * ld + k0 + kq * 8);
        lds[r * 8 + (kq ^ (r & 7))] = v;
    }
}

// EPI 0: out_bf16 = bf16(relu(acc+bias))          (h of FFN)
// EPI 1: xn = xold + BN(acc+bias); outf=xn; outb=bf16(xn)
// EPI 2: outf = acc+bias                          (VFR pre-gather)
template <int EPI>
__global__ __launch_bounds__(256)
void gemm_mfma(const unsigned short* __restrict__ A,
               const unsigned short* __restrict__ Bt,
               int M, int N, int K,
               const float* __restrict__ bias,
               const float* __restrict__ gam,
               const float* __restrict__ bet,
               const float* __restrict__ mean,
               const float* __restrict__ var,
               const float* __restrict__ xold,
               float* __restrict__ outf,
               unsigned short* __restrict__ outb)
{
    __shared__ bf16x8 As[1024];   // 16 KB
    __shared__ bf16x8 Bs[1024];   // 16 KB
    const int tid  = threadIdx.x;
    const int m0   = blockIdx.y * 128;
    const int n0   = blockIdx.x * 128;
    const int lane = tid & 63;
    const int wid  = tid >> 6;
    const int q    = lane >> 4;       // quad 0..3
    const int ln   = lane & 15;
    const int wm   = (wid >> 1) << 6; // wave row offset 0/64
    const int wn   = (wid & 1) << 6;  // wave col offset 0/64

    floatx4 acc[4][4];
    const floatx4 zero = {0.f, 0.f, 0.f, 0.f};
#pragma unroll
    for (int i = 0; i < 4; ++i)
#pragma unroll
        for (int j = 0; j < 4; ++j) acc[i][j] = zero;

    for (int k0 = 0; k0 < K; k0 += 64) {
        stage_tile(A,  K, m0, k0, As, tid);
        stage_tile(Bt, K, n0, k0, Bs, tid);
        __syncthreads();
#pragma unroll
        for (int ks = 0; ks < 2; ++ks) {
            bf16x8 af[4], bfr[4];
#pragma unroll
            for (int mt = 0; mt < 4; ++mt) {
                int m = wm + mt * 16 + ln;
                af[mt] = As[m * 8 + ((ks * 4 + q) ^ (m & 7))];
            }
#pragma unroll
            for (int nt = 0; nt < 4; ++nt) {
                int n = wn + nt * 16 + ln;
                bfr[nt] = Bs[n * 8 + ((ks * 4 + q) ^ (n & 7))];
            }
#pragma unroll
            for (int mt = 0; mt < 4; ++mt)
#pragma unroll
                for (int nt = 0; nt < 4; ++nt)
                    acc[mt][nt] = __builtin_amdgcn_mfma_f32_16x16x32_bf16(
                        af[mt], bfr[nt], acc[mt][nt], 0, 0, 0);
        }
        __syncthreads();
    }

    // C/D layout (m89-verified): col = lane&15, row = quad*4 + reg
#pragma unroll
    for (int nt = 0; nt < 4; ++nt) {
        const int c = n0 + wn + nt * 16 + ln;
        const float bia = bias[c];
        float sc = 0.f, bb = 0.f, mu = 0.f;
        if (EPI == 1) {
            sc = gam[c] * rsqrtf(var[c] + EPS);
            bb = bet[c];
            mu = mean[c];
        }
#pragma unroll
        for (int mt = 0; mt < 4; ++mt) {
#pragma unroll
            for (int r = 0; r < 4; ++r) {
                int row = m0 + wm + mt * 16 + q * 4 + r;
                float v = acc[mt][nt][r] + bia;
                size_t o = (size_t)row * N + c;
                if (EPI == 0) {
                    outb[o] = f2bf(v > 0.f ? v : 0.f);
                } else if (EPI == 1) {
                    float y  = (v - mu) * sc + bb;
                    float xn = xold[o] + y;
                    outf[o] = xn;
                    outb[o] = f2bf(xn);
                } else {
                    outf[o] = v;
                }
            }
        }
    }
}

// ---------------- VFR gather + edge max + BN + residual ----------------
// 2 points per 256-thread block; thread = channel. max_k(V[idx]) - V[self], BN, add.
__global__ __launch_bounds__(256)
void edge_max_bn(const float* __restrict__ V, const int* __restrict__ knn,
                 const float* __restrict__ gam, const float* __restrict__ bet,
                 const float* __restrict__ mean, const float* __restrict__ var,
                 float* __restrict__ x, unsigned short* __restrict__ xb)
{
    int tid = threadIdx.x;
    int c   = tid & 127;
    int p   = (blockIdx.x << 1) | (tid >> 7);   // global point 0..32767
    int b   = p >> 12;                          // batch (N=4096)
    const float selfv = V[(size_t)p * 128 + c];
    const int* kp = knn + (size_t)p * 16;
    size_t basev = ((size_t)b << 12) * 128;
    float mx = -3.4e38f;
#pragma unroll
    for (int k = 0; k < 16; ++k) {
        int idx = kp[k];
        mx = fmaxf(mx, V[basev + ((size_t)idx << 7) + c]);
    }
    float agg = mx - selfv;
    float y   = (agg - mean[c]) * (gam[c] * rsqrtf(var[c] + EPS)) + bet[c];
    size_t o  = (size_t)p * 128 + c;
    float xn  = x[o] + y;
    x[o]  = xn;
    xb[o] = f2bf(xn);
}

// ---------------- launch ----------------
extern "C" void kernel_launch(void* const* d_in, const int* in_sizes, int n_in,
                              void* d_out, int out_size, void* d_ws, size_t ws_size,
                              hipStream_t stream)
{
    const float* x_in = (const float*)d_in[0];
    const int*   knn  = (const int*)d_in[1];
    const float* w1  = (const float*)d_in[2];
    const float* b1  = (const float*)d_in[3];
    const float* w2  = (const float*)d_in[4];
    const float* b2  = (const float*)d_in[5];
    const float* g0  = (const float*)d_in[6];
    const float* be0 = (const float*)d_in[7];
    const float* m0p = (const float*)d_in[8];
    const float* v0p = (const float*)d_in[9];
    const float* vw  = (const float*)d_in[10];
    const float* vb  = (const float*)d_in[11];
    const float* vg  = (const float*)d_in[12];
    const float* vbe = (const float*)d_in[13];
    const float* vm  = (const float*)d_in[14];
    const float* vv  = (const float*)d_in[15];
    const float* fw1 = (const float*)d_in[16];
    const float* fb1 = (const float*)d_in[17];
    const float* fw2 = (const float*)d_in[18];
    const float* fb2 = (const float*)d_in[19];
    const float* fg  = (const float*)d_in[20];
    const float* fbe = (const float*)d_in[21];
    const float* fm  = (const float*)d_in[22];
    const float* fv  = (const float*)d_in[23];

    char* ws = (char*)d_ws;
    unsigned short* xb = (unsigned short*)(ws);                       // 8 MiB  [32768,128] bf16
    unsigned short* Hb = (unsigned short*)(ws + (size_t)(8 << 20));   // 32 MiB [32768,512] bf16
    float*          V  = (float*)(ws + (size_t)(40 << 20));           // 16 MiB [32768,128] f32
    unsigned short* wT = (unsigned short*)(ws + (size_t)(56 << 20));  // transposed bf16 weights
    unsigned short* w1T  = wT;            // [512,128]
    unsigned short* w2T  = wT + 65536;    // [128,512]
    unsigned short* vT0  = wT + 131072;   // [128,128]
    unsigned short* vT1  = wT + 147456;
    unsigned short* f1T0 = wT + 163840;   // [512,128]
    unsigned short* f1T1 = wT + 229376;
    unsigned short* f2T0 = wT + 294912;   // [128,512]
    unsigned short* f2T1 = wT + 360448;

    WPack p;
    p.w[0] = {w1,          w1T,  128, 512};
    p.w[1] = {w2,          w2T,  512, 128};
    p.w[2] = {vw,          vT0,  128, 128};
    p.w[3] = {vw + 16384,  vT1,  128, 128};
    p.w[4] = {fw1,         f1T0, 128, 512};
    p.w[5] = {fw1 + 65536, f1T1, 128, 512};
    p.w[6] = {fw2,         f2T0, 512, 128};
    p.w[7] = {fw2 + 65536, f2T1, 512, 128};
    conv_weights<<<dim3(256, 8), 256, 0, stream>>>(p);
    conv_x<<<dim3(4096), 256, 0, stream>>>(x_in, xb);

    float* xf = (float*)d_out;

    // FFN0: h = relu(x@w1+b1); x = x + BN(h@w2+b2)
    gemm_mfma<0><<<dim3(4, 256), 256, 0, stream>>>(xb, w1T, 32768, 512, 128,
        b1, nullptr, nullptr, nullptr, nullptr, nullptr, nullptr, Hb);
    gemm_mfma<1><<<dim3(1, 256), 256, 0, stream>>>(Hb, w2T, 32768, 128, 512,
        b2, g0, be0, m0p, v0p, x_in, xf, xb);

    for (int i = 0; i < 2; ++i) {
        const unsigned short* vTi = i ? vT1 : vT0;
        const unsigned short* f1  = i ? f1T1 : f1T0;
        const unsigned short* f2  = i ? f2T1 : f2T0;
        // VFR linear
        gemm_mfma<2><<<dim3(1, 256), 256, 0, stream>>>(xb, vTi, 32768, 128, 128,
            vb + i * 128, nullptr, nullptr, nullptr, nullptr, nullptr, V, nullptr);
        // gather + edge max + BN + residual
        edge_max_bn<<<dim3(16384), 256, 0, stream>>>(V, knn,
            vg + i * 128, vbe + i * 128, vm + i * 128, vv + i * 128, xf, xb);
        // FFN_i
        gemm_mfma<0><<<dim3(4, 256), 256, 0, stream>>>(xb, f1, 32768, 512, 128,
            fb1 + i * 512, nullptr, nullptr, nullptr, nullptr, nullptr, nullptr, Hb);
        gemm_mfma<1><<<dim3(1, 256), 256, 0, stream>>>(Hb, f2, 32768, 128, 512,
            fb2 + i * 128, fg + i * 128, fbe + i * 128, fm + i * 128, fv + i * 128,
            xf, xf, xb);
    }
}

// Round 2
// 261.817 us; speedup vs baseline: 1.1033x; 1.1033x over previous
//
#include <hip/hip_runtime.h>
#include <hip/hip_bf16.h>
#include <stdint.h>

typedef __attribute__((ext_vector_type(8))) __bf16 bf16x8;
typedef __attribute__((ext_vector_type(4))) float floatx4;

#define EPS 1e-5f

__device__ __forceinline__ unsigned short f2bf(float f) {
    union { float f; unsigned int u; } x; x.f = f;
    unsigned int r = x.u + 0x7fffu + ((x.u >> 16) & 1u);
    return (unsigned short)(r >> 16);
}

__device__ __forceinline__ float bf2f(unsigned int u) {
    union { unsigned int u; float f; } x; x.u = u << 16; return x.f;
}

// async 16B global->LDS DMA (DMA dest = wave-uniform base + lane*16)
__device__ __forceinline__ void async_copy16(const unsigned short* g, bf16x8* l) {
    __builtin_amdgcn_global_load_lds(
        (const __attribute__((address_space(1))) void*)g,
        (__attribute__((address_space(3))) void*)l, 16, 0, 0);
}

// ---------------- weight transpose + fp32->bf16 convert ----------------
struct WDesc { const float* src; unsigned short* dst; int rows; int cols; };
struct WPack { WDesc w[8]; };

__global__ void conv_weights(WPack p) {
    WDesc d = p.w[blockIdx.y];
    int i = blockIdx.x * 256 + threadIdx.x;
    int tot = d.rows * d.cols;
    if (i >= tot) return;
    int r = i / d.cols;
    int c = i - r * d.cols;
    d.dst[(size_t)c * d.rows + r] = f2bf(d.src[i]);   // dst = B^T [cols, rows]
}

__global__ void conv_x(const float* __restrict__ x, unsigned short* __restrict__ xb) {
    int i = blockIdx.x * 256 + threadIdx.x;
    const float4 v = ((const float4*)x)[i];
    ushort4 o;
    o.x = f2bf(v.x); o.y = f2bf(v.y); o.z = f2bf(v.z); o.w = f2bf(v.w);
    ((ushort4*)xb)[i] = o;
}

// ---------------- MFMA GEMM: C = A[M,K] * Bt[N,K]^T ----------------
// MT x 128 block tile, BK=64, 256 threads = 4 waves (2x2), wave tile (MT/2)x64.
// LDS layout: 16B chunks, chunk(r,kq) stored at r*8 + (kq ^ (r&7)).
// Staged with global_load_lds: lane l (LDS chunk idx=l) fetches global chunk
// (r=idx>>3, kq=(idx&7)^(r&7)) -- swizzle realized by permuting global addrs.
//
// EPI 0: outb = bf16(relu(acc+bias))                       (FFN hidden)
// EPI 1: xn = xold + BN(acc+bias); outf=xn; outb=bf16(xn)  (FFN out + residual)
// EPI 2: outb = bf16(acc+bias)                             (VFR pre-gather, bf16)
template <int EPI, int MT, int MINW>
__global__ __launch_bounds__(256, MINW)
void gemm_mfma(const unsigned short* __restrict__ A,
               const unsigned short* __restrict__ Bt,
               int M, int N, int K,
               const float* __restrict__ bias,
               const float* __restrict__ gam,
               const float* __restrict__ bet,
               const float* __restrict__ mean,
               const float* __restrict__ var,
               const float* __restrict__ xold,
               float* __restrict__ outf,
               unsigned short* __restrict__ outb)
{
    constexpr int AC = MT * 8;      // A-tile 16B chunks
    constexpr int WM = MT / 2;      // wave rows
    constexpr int MI = WM / 16;     // m-fragments per wave
    __shared__ bf16x8 As[AC];
    __shared__ bf16x8 Bs[1024];
    const int tid  = threadIdx.x;
    const int m0   = blockIdx.y * MT;
    const int n0   = blockIdx.x * 128;
    const int lane = tid & 63;
    const int wid  = tid >> 6;
    const int q    = lane >> 4;
    const int ln   = lane & 15;
    const int wm   = (wid >> 1) * WM;
    const int wn   = (wid & 1) << 6;

    floatx4 acc[MI][4];
    const floatx4 zero = {0.f, 0.f, 0.f, 0.f};
#pragma unroll
    for (int i = 0; i < MI; ++i)
#pragma unroll
        for (int j = 0; j < 4; ++j) acc[i][j] = zero;

    for (int k0 = 0; k0 < K; k0 += 64) {
#pragma unroll
        for (int i = 0; i < AC / 256; ++i) {
            int idx = i * 256 + tid;
            int r   = idx >> 3;
            int kq  = (idx & 7) ^ (r & 7);
            async_copy16(A + (size_t)(m0 + r) * K + k0 + kq * 8, &As[idx]);
        }
#pragma unroll
        for (int i = 0; i < 4; ++i) {
            int idx = i * 256 + tid;
            int r   = idx >> 3;
            int kq  = (idx & 7) ^ (r & 7);
            async_copy16(Bt + (size_t)(n0 + r) * K + k0 + kq * 8, &Bs[idx]);
        }
        __syncthreads();
#pragma unroll
        for (int ks = 0; ks < 2; ++ks) {
            bf16x8 af[MI], bfr[4];
#pragma unroll
            for (int mt = 0; mt < MI; ++mt) {
                int m = wm + mt * 16 + ln;
                af[mt] = As[m * 8 + ((ks * 4 + q) ^ (m & 7))];
            }
#pragma unroll
            for (int nt = 0; nt < 4; ++nt) {
                int n = wn + nt * 16 + ln;
                bfr[nt] = Bs[n * 8 + ((ks * 4 + q) ^ (n & 7))];
            }
#pragma unroll
            for (int mt = 0; mt < MI; ++mt)
#pragma unroll
                for (int nt = 0; nt < 4; ++nt)
                    acc[mt][nt] = __builtin_amdgcn_mfma_f32_16x16x32_bf16(
                        af[mt], bfr[nt], acc[mt][nt], 0, 0, 0);
        }
        __syncthreads();
    }

    // C/D layout (m89-verified): col = lane&15, row = quad*4 + reg
#pragma unroll
    for (int nt = 0; nt < 4; ++nt) {
        const int c = n0 + wn + nt * 16 + ln;
        const float bia = bias[c];
        float sc = 0.f, bb = 0.f, mu = 0.f;
        if (EPI == 1) {
            sc = gam[c] * rsqrtf(var[c] + EPS);
            bb = bet[c];
            mu = mean[c];
        }
#pragma unroll
        for (int mt = 0; mt < MI; ++mt) {
#pragma unroll
            for (int r = 0; r < 4; ++r) {
                int row = m0 + wm + mt * 16 + q * 4 + r;
                float v = acc[mt][nt][r] + bia;
                size_t o = (size_t)row * N + c;
                if (EPI == 0) {
                    outb[o] = f2bf(v > 0.f ? v : 0.f);
                } else if (EPI == 1) {
                    float y  = (v - mu) * sc + bb;
                    float xn = xold[o] + y;
                    outf[o] = xn;
                    outb[o] = f2bf(xn);
                } else {
                    outb[o] = f2bf(v);
                }
            }
        }
    }
}

// ---------------- VFR gather + edge max + BN + residual (bf16 V) ----------
// 1 point per wave, lane handles 2 channels (ushort2 = 4B/lane coalesced).
__global__ __launch_bounds__(256)
void edge_max_bn(const unsigned short* __restrict__ Vb, const int* __restrict__ knn,
                 const float* __restrict__ gam, const float* __restrict__ bet,
                 const float* __restrict__ mean, const float* __restrict__ var,
                 float* __restrict__ x, unsigned short* __restrict__ xb)
{
    const int tid  = threadIdx.x;
    const int lane = tid & 63;
    const int p    = (blockIdx.x << 2) | (tid >> 6);   // point 0..32767
    const int b    = p >> 12;                          // batch (N=4096)
    const int c0   = lane << 1;
    const size_t rowoff = (size_t)p * 128 + c0;

    unsigned int su = *(const unsigned int*)(Vb + rowoff);
    float s0 = bf2f(su & 0xffffu), s1 = bf2f(su >> 16);

    const int* kp = knn + (size_t)p * 16;
    const unsigned short* vbase = Vb + (((size_t)b << 12) << 7) + c0;
    float m0 = -3.4e38f, m1 = -3.4e38f;
#pragma unroll
    for (int k = 0; k < 16; ++k) {
        unsigned int u = *(const unsigned int*)(vbase + ((size_t)kp[k] << 7));
        m0 = fmaxf(m0, bf2f(u & 0xffffu));
        m1 = fmaxf(m1, bf2f(u >> 16));
    }
    float2 gv = *(const float2*)(gam + c0);
    float2 bv = *(const float2*)(bet + c0);
    float2 mv = *(const float2*)(mean + c0);
    float2 vv = *(const float2*)(var + c0);
    float y0 = (m0 - s0 - mv.x) * (gv.x * rsqrtf(vv.x + EPS)) + bv.x;
    float y1 = (m1 - s1 - mv.y) * (gv.y * rsqrtf(vv.y + EPS)) + bv.y;
    float2 xv = *(const float2*)(x + rowoff);
    float xn0 = xv.x + y0, xn1 = xv.y + y1;
    *(float2*)(x + rowoff) = make_float2(xn0, xn1);
    *(unsigned int*)(xb + rowoff) =
        (unsigned int)f2bf(xn0) | ((unsigned int)f2bf(xn1) << 16);
}

// ---------------- launch ----------------
extern "C" void kernel_launch(void* const* d_in, const int* in_sizes, int n_in,
                              void* d_out, int out_size, void* d_ws, size_t ws_size,
                              hipStream_t stream)
{
    const float* x_in = (const float*)d_in[0];
    const int*   knn  = (const int*)d_in[1];
    const float* w1  = (const float*)d_in[2];
    const float* b1  = (const float*)d_in[3];
    const float* w2  = (const float*)d_in[4];
    const float* b2  = (const float*)d_in[5];
    const float* g0  = (const float*)d_in[6];
    const float* be0 = (const float*)d_in[7];
    const float* m0p = (const float*)d_in[8];
    const float* v0p = (const float*)d_in[9];
    const float* vw  = (const float*)d_in[10];
    const float* vb  = (const float*)d_in[11];
    const float* vg  = (const float*)d_in[12];
    const float* vbe = (const float*)d_in[13];
    const float* vm  = (const float*)d_in[14];
    const float* vv  = (const float*)d_in[15];
    const float* fw1 = (const float*)d_in[16];
    const float* fb1 = (const float*)d_in[17];
    const float* fw2 = (const float*)d_in[18];
    const float* fb2 = (const float*)d_in[19];
    const float* fg  = (const float*)d_in[20];
    const float* fbe = (const float*)d_in[21];
    const float* fm  = (const float*)d_in[22];
    const float* fv  = (const float*)d_in[23];

    char* ws = (char*)d_ws;
    unsigned short* xb = (unsigned short*)(ws);                       // 8 MiB  [32768,128] bf16
    unsigned short* Hb = (unsigned short*)(ws + (size_t)(8 << 20));   // 32 MiB [32768,512] bf16
    unsigned short* Vb = (unsigned short*)(ws + (size_t)(40 << 20));  // 8 MiB  [32768,128] bf16
    unsigned short* wT = (unsigned short*)(ws + (size_t)(56 << 20));  // transposed bf16 weights
    unsigned short* w1T  = wT;            // [512,128]
    unsigned short* w2T  = wT + 65536;    // [128,512]
    unsigned short* vT0  = wT + 131072;   // [128,128]
    unsigned short* vT1  = wT + 147456;
    unsigned short* f1T0 = wT + 163840;   // [512,128]
    unsigned short* f1T1 = wT + 229376;
    unsigned short* f2T0 = wT + 294912;   // [128,512]
    unsigned short* f2T1 = wT + 360448;

    WPack p;
    p.w[0] = {w1,          w1T,  128, 512};
    p.w[1] = {w2,          w2T,  512, 128};
    p.w[2] = {vw,          vT0,  128, 128};
    p.w[3] = {vw + 16384,  vT1,  128, 128};
    p.w[4] = {fw1,         f1T0, 128, 512};
    p.w[5] = {fw1 + 65536, f1T1, 128, 512};
    p.w[6] = {fw2,         f2T0, 512, 128};
    p.w[7] = {fw2 + 65536, f2T1, 512, 128};
    conv_weights<<<dim3(256, 8), 256, 0, stream>>>(p);
    conv_x<<<dim3(4096), 256, 0, stream>>>(x_in, xb);

    float* xf = (float*)d_out;

    // FFN0: h = relu(x@w1+b1); x = x + BN(h@w2+b2)
    gemm_mfma<0, 128, 3><<<dim3(4, 256), 256, 0, stream>>>(xb, w1T, 32768, 512, 128,
        b1, nullptr, nullptr, nullptr, nullptr, nullptr, nullptr, Hb);
    gemm_mfma<1, 64, 2><<<dim3(1, 512), 256, 0, stream>>>(Hb, w2T, 32768, 128, 512,
        b2, g0, be0, m0p, v0p, x_in, xf, xb);

    for (int i = 0; i < 2; ++i) {
        const unsigned short* vTi = i ? vT1 : vT0;
        const unsigned short* f1  = i ? f1T1 : f1T0;
        const unsigned short* f2  = i ? f2T1 : f2T0;
        // VFR linear -> bf16 V
        gemm_mfma<2, 64, 2><<<dim3(1, 512), 256, 0, stream>>>(xb, vTi, 32768, 128, 128,
            vb + i * 128, nullptr, nullptr, nullptr, nullptr, nullptr, nullptr, Vb);
        // gather + edge max + BN + residual
        edge_max_bn<<<dim3(8192), 256, 0, stream>>>(Vb, knn,
            vg + i * 128, vbe + i * 128, vm + i * 128, vv + i * 128, xf, xb);
        // FFN_i
        gemm_mfma<0, 128, 3><<<dim3(4, 256), 256, 0, stream>>>(xb, f1, 32768, 512, 128,
            fb1 + i * 512, nullptr, nullptr, nullptr, nullptr, nullptr, nullptr, Hb);
        gemm_mfma<1, 64, 2><<<dim3(1, 512), 256, 0, stream>>>(Hb, f2, 32768, 128, 512,
            fb2 + i * 128, fg + i * 128, fbe + i * 128, fm + i * 128, fv + i * 128,
            xf, xf, xb);
    }
}

// Round 3
// 247.099 us; speedup vs baseline: 1.1690x; 1.0596x over previous
//
#include <hip/hip_runtime.h>
#include <hip/hip_bf16.h>
#include <stdint.h>

typedef __attribute__((ext_vector_type(8))) __bf16 bf16x8;
typedef __attribute__((ext_vector_type(4))) float floatx4;

#define EPS 1e-5f

__device__ __forceinline__ unsigned short f2bf(float f) {
    union { float f; unsigned int u; } x; x.f = f;
    unsigned int r = x.u + 0x7fffu + ((x.u >> 16) & 1u);
    return (unsigned short)(r >> 16);
}

__device__ __forceinline__ float bf2f(unsigned int u) {
    union { unsigned int u; float f; } x; x.u = u << 16; return x.f;
}

// async 16B global->LDS DMA (dest = wave-uniform base + lane*16)
__device__ __forceinline__ void async_copy16(const unsigned short* g, bf16x8* l) {
    __builtin_amdgcn_global_load_lds(
        (const __attribute__((address_space(1))) void*)g,
        (__attribute__((address_space(3))) void*)l, 16, 0, 0);
}

// ---------------- weight transpose + fp32->bf16 convert ----------------
struct WDesc { const float* src; unsigned short* dst; int rows; int cols; };
struct WPack { WDesc w[8]; };

__global__ void conv_weights(WPack p) {
    WDesc d = p.w[blockIdx.y];
    int i = blockIdx.x * 256 + threadIdx.x;
    int tot = d.rows * d.cols;
    if (i >= tot) return;
    int r = i / d.cols;
    int c = i - r * d.cols;
    d.dst[(size_t)c * d.rows + r] = f2bf(d.src[i]);   // dst = src^T [cols, rows]
}

__global__ void conv_x(const float* __restrict__ x, unsigned short* __restrict__ xb) {
    int i = blockIdx.x * 256 + threadIdx.x;
    const float4 v = ((const float4*)x)[i];
    ushort4 o;
    o.x = f2bf(v.x); o.y = f2bf(v.y); o.z = f2bf(v.z); o.w = f2bf(v.w);
    ((ushort4*)xb)[i] = o;
}

// ================= fused FFN: x += BN(relu(x@W1+b1)@W2+b2) =================
// One block = 64 points, 256 threads = 4 waves.
// GEMM1 computes h^T (M=512 hidden, N=64 points, K=128 chan); wave w owns
// hidden slice [128w,128w+128). A=W1T[512][128], B=x rows — both as direct
// per-lane 16B fragment loads from global (L2-hot weights, L1-hot x tile).
// h packed to bf16 in-register, written to LDS [point][hidden] (16B-chunk
// XOR swizzle). One barrier. GEMM2 (M=64 points, N=128 chan, K=512 hidden);
// wave w owns chan slice [32w,32w+32); A-frags = ds_read_b128 from h tile,
// B=W2T[128][512] direct from global. Epilogue: bias+BN+residual.
__global__ __launch_bounds__(256, 2)
void ffn_fused(const unsigned short* __restrict__ xbsrc,
               const unsigned short* __restrict__ W1T,   // [512][128]
               const float* __restrict__ b1,
               const unsigned short* __restrict__ W2T,   // [128][512]
               const float* __restrict__ b2,
               const float* __restrict__ gam,
               const float* __restrict__ bet,
               const float* __restrict__ mean,
               const float* __restrict__ var,
               const float* __restrict__ xold,
               float* __restrict__ xf,
               unsigned short* __restrict__ xbout)
{
    __shared__ __align__(16) uint2 hsm[64 * 128];   // 64 KB: [point][hid 16B-chunk ^ sw]
    const int tid  = threadIdx.x;
    const int lane = tid & 63;
    const int w    = tid >> 6;
    const int q    = lane >> 4;
    const int ln   = lane & 15;
    const int sw   = ln & 7;
    const int p0   = blockIdx.x << 6;

    // ---- GEMM1 ----
    floatx4 acc1[8][4];
    const floatx4 zero = {0.f, 0.f, 0.f, 0.f};
#pragma unroll
    for (int i = 0; i < 8; ++i)
#pragma unroll
        for (int j = 0; j < 4; ++j) acc1[i][j] = zero;

    const unsigned short* abase = W1T + ((size_t)(128 * w + ln)) * 128 + 8 * q;
    const unsigned short* bbase = xbsrc + ((size_t)(p0 + ln)) * 128 + 8 * q;
#pragma unroll
    for (int ks = 0; ks < 4; ++ks) {
        bf16x8 bfr[4];
#pragma unroll
        for (int nt = 0; nt < 4; ++nt)
            bfr[nt] = *(const bf16x8*)(bbase + nt * (16 * 128) + ks * 32);
#pragma unroll
        for (int mt = 0; mt < 8; ++mt) {
            bf16x8 af = *(const bf16x8*)(abase + mt * (16 * 128) + ks * 32);
#pragma unroll
            for (int nt = 0; nt < 4; ++nt)
                acc1[mt][nt] = __builtin_amdgcn_mfma_f32_16x16x32_bf16(
                    af, bfr[nt], acc1[mt][nt], 0, 0, 0);
        }
    }

    // ---- epilogue1: +b1, relu, pack bf16x4, ds_write ----
#pragma unroll
    for (int mt = 0; mt < 8; ++mt) {
        const int hid = 128 * w + 16 * mt + 4 * q;
        const float bv0 = b1[hid + 0], bv1 = b1[hid + 1];
        const float bv2 = b1[hid + 2], bv3 = b1[hid + 3];
        const int c16  = 16 * w + 2 * mt + (q >> 1);   // 16B chunk index
        const int slot = ((c16 ^ sw) << 1) + (q & 1);
#pragma unroll
        for (int nt = 0; nt < 4; ++nt) {
            const int p = 16 * nt + ln;
            float v0 = acc1[mt][nt][0] + bv0; v0 = v0 > 0.f ? v0 : 0.f;
            float v1 = acc1[mt][nt][1] + bv1; v1 = v1 > 0.f ? v1 : 0.f;
            float v2 = acc1[mt][nt][2] + bv2; v2 = v2 > 0.f ? v2 : 0.f;
            float v3 = acc1[mt][nt][3] + bv3; v3 = v3 > 0.f ? v3 : 0.f;
            uint2 pk;
            pk.x = (unsigned int)f2bf(v0) | ((unsigned int)f2bf(v1) << 16);
            pk.y = (unsigned int)f2bf(v2) | ((unsigned int)f2bf(v3) << 16);
            hsm[(p << 7) + slot] = pk;
        }
    }
    __syncthreads();

    // ---- GEMM2 ----
    floatx4 acc2[4][2];
#pragma unroll
    for (int i = 0; i < 4; ++i)
#pragma unroll
        for (int j = 0; j < 2; ++j) acc2[i][j] = zero;

    const unsigned short* b2base = W2T + ((size_t)(32 * w + ln)) * 512 + 8 * q;
#pragma unroll
    for (int ks = 0; ks < 16; ++ks) {
        bf16x8 bfr2[2];
#pragma unroll
        for (int nt = 0; nt < 2; ++nt)
            bfr2[nt] = *(const bf16x8*)(b2base + nt * (16 * 512) + ks * 32);
        const int c16 = 4 * ks + q;
#pragma unroll
        for (int mt = 0; mt < 4; ++mt) {
            const int p = 16 * mt + ln;
            bf16x8 af2 = *(const bf16x8*)&hsm[(p << 7) + ((c16 ^ sw) << 1)];
#pragma unroll
            for (int nt = 0; nt < 2; ++nt)
                acc2[mt][nt] = __builtin_amdgcn_mfma_f32_16x16x32_bf16(
                    af2, bfr2[nt], acc2[mt][nt], 0, 0, 0);
        }
    }

    // ---- epilogue2: +b2, BN, residual ----
#pragma unroll
    for (int nt = 0; nt < 2; ++nt) {
        const int c = 32 * w + 16 * nt + ln;
        const float bia = b2[c];
        const float sc  = gam[c] * rsqrtf(var[c] + EPS);
        const float bb  = bet[c];
        const float mu  = mean[c];
#pragma unroll
        for (int mt = 0; mt < 4; ++mt) {
#pragma unroll
            for (int r = 0; r < 4; ++r) {
                const int row = p0 + 16 * mt + 4 * q + r;
                const size_t o = (size_t)row * 128 + c;
                float v  = acc2[mt][nt][r] + bia;
                float y  = (v - mu) * sc + bb;
                float xn = xold[o] + y;
                xf[o]    = xn;
                xbout[o] = f2bf(xn);
            }
        }
    }
}

// ---------------- MFMA GEMM (VFR linear): C = A[M,K] * Bt[N,K]^T ----------
template <int EPI, int MT, int MINW>
__global__ __launch_bounds__(256, MINW)
void gemm_mfma(const unsigned short* __restrict__ A,
               const unsigned short* __restrict__ Bt,
               int M, int N, int K,
               const float* __restrict__ bias,
               unsigned short* __restrict__ outb)
{
    constexpr int AC = MT * 8;
    constexpr int WM = MT / 2;
    constexpr int MI = WM / 16;
    __shared__ bf16x8 As[AC];
    __shared__ bf16x8 Bs[1024];
    const int tid  = threadIdx.x;
    const int m0   = blockIdx.y * MT;
    const int n0   = blockIdx.x * 128;
    const int lane = tid & 63;
    const int wid  = tid >> 6;
    const int q    = lane >> 4;
    const int ln   = lane & 15;
    const int wm   = (wid >> 1) * WM;
    const int wn   = (wid & 1) << 6;

    floatx4 acc[MI][4];
    const floatx4 zero = {0.f, 0.f, 0.f, 0.f};
#pragma unroll
    for (int i = 0; i < MI; ++i)
#pragma unroll
        for (int j = 0; j < 4; ++j) acc[i][j] = zero;

    for (int k0 = 0; k0 < K; k0 += 64) {
#pragma unroll
        for (int i = 0; i < AC / 256; ++i) {
            int idx = i * 256 + tid;
            int r   = idx >> 3;
            int kq  = (idx & 7) ^ (r & 7);
            async_copy16(A + (size_t)(m0 + r) * K + k0 + kq * 8, &As[idx]);
        }
#pragma unroll
        for (int i = 0; i < 4; ++i) {
            int idx = i * 256 + tid;
            int r   = idx >> 3;
            int kq  = (idx & 7) ^ (r & 7);
            async_copy16(Bt + (size_t)(n0 + r) * K + k0 + kq * 8, &Bs[idx]);
        }
        __syncthreads();
#pragma unroll
        for (int ks = 0; ks < 2; ++ks) {
            bf16x8 af[MI], bfr[4];
#pragma unroll
            for (int mt = 0; mt < MI; ++mt) {
                int m = wm + mt * 16 + ln;
                af[mt] = As[m * 8 + ((ks * 4 + q) ^ (m & 7))];
            }
#pragma unroll
            for (int nt = 0; nt < 4; ++nt) {
                int n = wn + nt * 16 + ln;
                bfr[nt] = Bs[n * 8 + ((ks * 4 + q) ^ (n & 7))];
            }
#pragma unroll
            for (int mt = 0; mt < MI; ++mt)
#pragma unroll
                for (int nt = 0; nt < 4; ++nt)
                    acc[mt][nt] = __builtin_amdgcn_mfma_f32_16x16x32_bf16(
                        af[mt], bfr[nt], acc[mt][nt], 0, 0, 0);
        }
        __syncthreads();
    }

#pragma unroll
    for (int nt = 0; nt < 4; ++nt) {
        const int c = n0 + wn + nt * 16 + ln;
        const float bia = bias[c];
#pragma unroll
        for (int mt = 0; mt < MI; ++mt) {
#pragma unroll
            for (int r = 0; r < 4; ++r) {
                int row = m0 + wm + mt * 16 + q * 4 + r;
                float v = acc[mt][nt][r] + bia;
                outb[(size_t)row * N + c] = f2bf(v);
            }
        }
    }
}

// ---------------- VFR gather + edge max + BN + residual (bf16 V) ----------
__global__ __launch_bounds__(256)
void edge_max_bn(const unsigned short* __restrict__ Vb, const int* __restrict__ knn,
                 const float* __restrict__ gam, const float* __restrict__ bet,
                 const float* __restrict__ mean, const float* __restrict__ var,
                 float* __restrict__ x, unsigned short* __restrict__ xb)
{
    const int tid  = threadIdx.x;
    const int lane = tid & 63;
    const int p    = (blockIdx.x << 2) | (tid >> 6);
    const int b    = p >> 12;
    const int c0   = lane << 1;
    const size_t rowoff = (size_t)p * 128 + c0;

    unsigned int su = *(const unsigned int*)(Vb + rowoff);
    float s0 = bf2f(su & 0xffffu), s1 = bf2f(su >> 16);

    const int* kp = knn + (size_t)p * 16;
    const unsigned short* vbase = Vb + (((size_t)b << 12) << 7) + c0;
    float m0 = -3.4e38f, m1 = -3.4e38f;
#pragma unroll
    for (int k = 0; k < 16; ++k) {
        unsigned int u = *(const unsigned int*)(vbase + ((size_t)kp[k] << 7));
        m0 = fmaxf(m0, bf2f(u & 0xffffu));
        m1 = fmaxf(m1, bf2f(u >> 16));
    }
    float2 gv = *(const float2*)(gam + c0);
    float2 bv = *(const float2*)(bet + c0);
    float2 mv = *(const float2*)(mean + c0);
    float2 vv = *(const float2*)(var + c0);
    float y0 = (m0 - s0 - mv.x) * (gv.x * rsqrtf(vv.x + EPS)) + bv.x;
    float y1 = (m1 - s1 - mv.y) * (gv.y * rsqrtf(vv.y + EPS)) + bv.y;
    float2 xv = *(const float2*)(x + rowoff);
    float xn0 = xv.x + y0, xn1 = xv.y + y1;
    *(float2*)(x + rowoff) = make_float2(xn0, xn1);
    *(unsigned int*)(xb + rowoff) =
        (unsigned int)f2bf(xn0) | ((unsigned int)f2bf(xn1) << 16);
}

// ---------------- launch ----------------
extern "C" void kernel_launch(void* const* d_in, const int* in_sizes, int n_in,
                              void* d_out, int out_size, void* d_ws, size_t ws_size,
                              hipStream_t stream)
{
    const float* x_in = (const float*)d_in[0];
    const int*   knn  = (const int*)d_in[1];
    const float* w1  = (const float*)d_in[2];
    const float* b1  = (const float*)d_in[3];
    const float* w2  = (const float*)d_in[4];
    const float* b2  = (const float*)d_in[5];
    const float* g0  = (const float*)d_in[6];
    const float* be0 = (const float*)d_in[7];
    const float* m0p = (const float*)d_in[8];
    const float* v0p = (const float*)d_in[9];
    const float* vw  = (const float*)d_in[10];
    const float* vb  = (const float*)d_in[11];
    const float* vg  = (const float*)d_in[12];
    const float* vbe = (const float*)d_in[13];
    const float* vm  = (const float*)d_in[14];
    const float* vv  = (const float*)d_in[15];
    const float* fw1 = (const float*)d_in[16];
    const float* fb1 = (const float*)d_in[17];
    const float* fw2 = (const float*)d_in[18];
    const float* fb2 = (const float*)d_in[19];
    const float* fg  = (const float*)d_in[20];
    const float* fbe = (const float*)d_in[21];
    const float* fm  = (const float*)d_in[22];
    const float* fv  = (const float*)d_in[23];

    char* ws = (char*)d_ws;
    unsigned short* xb = (unsigned short*)(ws);                       // 8 MiB
    unsigned short* Vb = (unsigned short*)(ws + (size_t)(8 << 20));   // 8 MiB
    unsigned short* wT = (unsigned short*)(ws + (size_t)(16 << 20));
    unsigned short* w1T  = wT;            // [512,128]
    unsigned short* w2T  = wT + 65536;    // [128,512]
    unsigned short* vT0  = wT + 131072;   // [128,128]
    unsigned short* vT1  = wT + 147456;
    unsigned short* f1T0 = wT + 163840;   // [512,128]
    unsigned short* f1T1 = wT + 229376;
    unsigned short* f2T0 = wT + 294912;   // [128,512]
    unsigned short* f2T1 = wT + 360448;

    WPack p;
    p.w[0] = {w1,          w1T,  128, 512};
    p.w[1] = {w2,          w2T,  512, 128};
    p.w[2] = {vw,          vT0,  128, 128};
    p.w[3] = {vw + 16384,  vT1,  128, 128};
    p.w[4] = {fw1,         f1T0, 128, 512};
    p.w[5] = {fw1 + 65536, f1T1, 128, 512};
    p.w[6] = {fw2,         f2T0, 512, 128};
    p.w[7] = {fw2 + 65536, f2T1, 512, 128};
    conv_weights<<<dim3(256, 8), 256, 0, stream>>>(p);
    conv_x<<<dim3(4096), 256, 0, stream>>>(x_in, xb);

    float* xf = (float*)d_out;

    // FFN0
    ffn_fused<<<dim3(512), 256, 0, stream>>>(xb, w1T, b1, w2T, b2,
        g0, be0, m0p, v0p, x_in, xf, xb);

    for (int i = 0; i < 2; ++i) {
        const unsigned short* vTi = i ? vT1 : vT0;
        const unsigned short* f1  = i ? f1T1 : f1T0;
        const unsigned short* f2  = i ? f2T1 : f2T0;
        // VFR linear -> bf16 V
        gemm_mfma<2, 64, 2><<<dim3(1, 512), 256, 0, stream>>>(xb, vTi, 32768, 128, 128,
            vb + i * 128, Vb);
        // gather + edge max + BN + residual
        edge_max_bn<<<dim3(8192), 256, 0, stream>>>(Vb, knn,
            vg + i * 128, vbe + i * 128, vm + i * 128, vv + i * 128, xf, xb);
        // FFN_i
        ffn_fused<<<dim3(512), 256, 0, stream>>>(xb, f1, fb1 + i * 512, f2, fb2 + i * 128,
            fg + i * 128, fbe + i * 128, fm + i * 128, fv + i * 128, xf, xf, xb);
    }
}

// Round 5
// 237.535 us; speedup vs baseline: 1.2160x; 1.0403x over previous
//
#include <hip/hip_runtime.h>
#include <hip/hip_bf16.h>
#include <stdint.h>

typedef __attribute__((ext_vector_type(8))) __bf16 bf16x8;
typedef __attribute__((ext_vector_type(4))) float floatx4;

#define EPS 1e-5f

__device__ __forceinline__ unsigned short f2bf(float f) {
    union { float f; unsigned int u; } x; x.f = f;
    unsigned int r = x.u + 0x7fffu + ((x.u >> 16) & 1u);
    return (unsigned short)(r >> 16);
}

__device__ __forceinline__ float bf2f(unsigned int u) {
    union { unsigned int u; float f; } x; x.u = u << 16; return x.f;
}

struct Params {
    const float* x_in;
    const int*   knn;
    const float* w1s[3];   // [128][512]
    const float* w2s[3];   // [512][128]
    const float* vws[2];   // [128][128]
    unsigned short* W1P[3];
    unsigned short* W2P[3];
    unsigned short* VTP[2];
    const float* b1s[3];
    const float* b2s[3];
    const float* gs[3];
    const float* bes[3];
    const float* ms[3];
    const float* vvs[3];
    const float* vbb[2];
    const float* vgg[2];
    const float* vbt[2];
    const float* vmm[2];
    const float* vva[2];
    float* xf;
};

// ---------------- pack weights fragment-major (bf16) ----------------
// W1P frag addr = hf*32768 + w*8192 + mt*2048 + ks*512 + q*128 + ln*8 + j
//   = W1[c=32ks+8q+j][h=256hf+64w+16mt+ln]
// W2P frag addr = hf*32768 + w*8192 + nt*4096 + ks*512 + q*128 + ln*8 + j
//   = W2[h=256hf+32ks+8q+j][c=32w+16nt+ln]
// VTP frag addr = hfv*8192 + nt*2048 + ks*512 + q*128 + ln*8 + j
//   = Wv[k=32ks+8q+j][c=64hfv+16nt+ln]
__global__ __launch_bounds__(256) void pack_weights(Params P) {
    const int gtid = blockIdx.x * 256 + threadIdx.x;
    const int GT   = gridDim.x * 256;
#pragma unroll
    for (int t = 0; t < 3; ++t) {
        const float* s1 = P.w1s[t];
        unsigned short* d1 = P.W1P[t];
        for (int e = gtid; e < 65536; e += GT) {
            int j = e & 7, ci = e >> 3;
            int ln = ci & 15, q = (ci >> 4) & 3, ks = (ci >> 6) & 3;
            int mt = (ci >> 8) & 3, w = (ci >> 10) & 3, hf = (ci >> 12) & 1;
            int h = 256 * hf + 64 * w + 16 * mt + ln;
            int c = 32 * ks + 8 * q + j;
            d1[e] = f2bf(s1[c * 512 + h]);
        }
        const float* s2 = P.w2s[t];
        unsigned short* d2 = P.W2P[t];
        for (int e = gtid; e < 65536; e += GT) {
            int j = e & 7, ci = e >> 3;
            int ln = ci & 15, q = (ci >> 4) & 3, ks = (ci >> 6) & 7;
            int nt = (ci >> 9) & 1, w = (ci >> 10) & 3, hf = (ci >> 12) & 1;
            int h = 256 * hf + 32 * ks + 8 * q + j;
            int c = 32 * w + 16 * nt + ln;
            d2[e] = f2bf(s2[h * 128 + c]);
        }
    }
#pragma unroll
    for (int t = 0; t < 2; ++t) {
        const float* sv = P.vws[t];
        unsigned short* dv = P.VTP[t];
        for (int e = gtid; e < 16384; e += GT) {
            int j = e & 7, ci = e >> 3;
            int ln = ci & 15, q = (ci >> 4) & 3, ks = (ci >> 6) & 3;
            int nt = (ci >> 8) & 3, hfv = (ci >> 10) & 1;
            int k = 32 * ks + 8 * q + j;
            int c = 64 * hfv + 16 * nt + ln;
            dv[e] = f2bf(sv[k * 128 + c]);
        }
    }
}

// ---------------- fused stage kernel ----------------
// One block = 64 points (rows p0..p0+63). Phases:
//  [LOADX]  x_in fp32 -> LDS x tile (bf16, swizzled)          (K1 only)
//  [TE>=0]  edge: x += BN(max_k VbIn[knn]-VbIn[self]); x tile (K2,K3)
//  FFN TF:  hidden-split x2; h tile in LDS; x += BN(ffn)      (all)
//  [TV>=0]  VFR: VbOut = bf16(x @ Wv + vb)                    (K1,K2)
// x tile: 64 rows x 128 ch bf16; 16B chunk (r,kq) at r*16+(kq^(r&7))
// h tile: 64 pts x 256 hid bf16; chunk (p,c16) at p*32+(c16^(p&7))
template <int LOADX, int TE, int TF, int TV>
__global__ __launch_bounds__(256, 2)
void stage(Params P, const float* __restrict__ xold,
           const unsigned short* __restrict__ VbIn,
           unsigned short* __restrict__ VbOut)
{
    __shared__ __align__(16) unsigned short xt[8192];   // 16 KB
    __shared__ __align__(16) uint2 ht2[4096];           // 32 KB
    const int tid  = threadIdx.x;
    const int lane = tid & 63;
    const int w    = tid >> 6;
    const int q    = lane >> 4;
    const int ln   = lane & 15;
    const int sw   = ln & 7;
    const int p0   = blockIdx.x << 6;
    const floatx4 zero = {0.f, 0.f, 0.f, 0.f};

    if constexpr (LOADX) {
        const int r  = tid >> 2, qt = tid & 3;
        const float4* src = (const float4*)(xold + (size_t)(p0 + r) * 128 + qt * 32);
#pragma unroll
        for (int i = 0; i < 4; ++i) {
            float4 a = src[i * 2];
            float4 b = src[i * 2 + 1];
            int kq = qt * 4 + i;
            uint4 pk;
            pk.x = (unsigned int)f2bf(a.x) | ((unsigned int)f2bf(a.y) << 16);
            pk.y = (unsigned int)f2bf(a.z) | ((unsigned int)f2bf(a.w) << 16);
            pk.z = (unsigned int)f2bf(b.x) | ((unsigned int)f2bf(b.y) << 16);
            pk.w = (unsigned int)f2bf(b.z) | ((unsigned int)f2bf(b.w) << 16);
            *(uint4*)&xt[(r * 16 + (kq ^ (r & 7))) * 8] = pk;
        }
    }

    if constexpr (TE >= 0) {
        const int c0 = lane << 1;
        float2 gv = *(const float2*)(P.vgg[TE] + c0);
        float2 bv = *(const float2*)(P.vbt[TE] + c0);
        float2 mv = *(const float2*)(P.vmm[TE] + c0);
        float2 vv = *(const float2*)(P.vva[TE] + c0);
        const float sc0 = gv.x * rsqrtf(vv.x + EPS);
        const float sc1 = gv.y * rsqrtf(vv.y + EPS);
        for (int it = 0; it < 16; ++it) {
            const int pl = it * 4 + w;
            const int p  = p0 + pl;
            const int b  = p >> 12;
            const size_t rowoff = (size_t)p * 128 + c0;
            unsigned int su = *(const unsigned int*)(VbIn + rowoff);
            float s0 = bf2f(su & 0xffffu), s1 = bf2f(su >> 16);
            const int* kp = P.knn + (size_t)p * 16;
            const unsigned short* vbase = VbIn + (((size_t)b << 12) << 7) + c0;
            float m0 = -3.4e38f, m1 = -3.4e38f;
#pragma unroll
            for (int k = 0; k < 16; ++k) {
                unsigned int u = *(const unsigned int*)(vbase + ((size_t)kp[k] << 7));
                m0 = fmaxf(m0, bf2f(u & 0xffffu));
                m1 = fmaxf(m1, bf2f(u >> 16));
            }
            float y0 = (m0 - s0 - mv.x) * sc0 + bv.x;
            float y1 = (m1 - s1 - mv.y) * sc1 + bv.y;
            float2 xv = *(const float2*)(P.xf + rowoff);
            float xn0 = xv.x + y0, xn1 = xv.y + y1;
            *(float2*)(P.xf + rowoff) = make_float2(xn0, xn1);
            unsigned int pk = (unsigned int)f2bf(xn0) | ((unsigned int)f2bf(xn1) << 16);
            ((unsigned int*)xt)[(pl * 16 + ((lane >> 2) ^ (pl & 7))) * 4 + (lane & 3)] = pk;
        }
    }
    __syncthreads();

    // ---------------- FFN (hidden split x2) ----------------
    floatx4 acc2[4][2];
#pragma unroll
    for (int i = 0; i < 4; ++i)
#pragma unroll
        for (int j = 0; j < 2; ++j) acc2[i][j] = zero;

    const unsigned short* W1 = P.W1P[TF];
    const unsigned short* W2 = P.W2P[TF];
    const float* b1 = P.b1s[TF];

#pragma unroll
    for (int hf = 0; hf < 2; ++hf) {
        floatx4 acc1[4][4];
#pragma unroll
        for (int i = 0; i < 4; ++i)
#pragma unroll
            for (int j = 0; j < 4; ++j) acc1[i][j] = zero;

        const unsigned short* a1 = W1 + hf * 32768 + w * 8192 + q * 128 + ln * 8;
#pragma unroll
        for (int ks = 0; ks < 4; ++ks) {
            bf16x8 bfr[4];
#pragma unroll
            for (int nt = 0; nt < 4; ++nt)
                bfr[nt] = *(const bf16x8*)&xt[((16 * nt + ln) * 16 + ((4 * ks + q) ^ sw)) * 8];
#pragma unroll
            for (int mt = 0; mt < 4; ++mt) {
                bf16x8 af = *(const bf16x8*)(a1 + mt * 2048 + ks * 512);
#pragma unroll
                for (int nt = 0; nt < 4; ++nt)
                    acc1[mt][nt] = __builtin_amdgcn_mfma_f32_16x16x32_bf16(
                        af, bfr[nt], acc1[mt][nt], 0, 0, 0);
            }
        }
        // epilogue1 -> h tile
#pragma unroll
        for (int mt = 0; mt < 4; ++mt) {
            const int hh   = 64 * w + 16 * mt + 4 * q;
            const int ghid = 256 * hf + hh;
            const float bv0 = b1[ghid + 0], bv1 = b1[ghid + 1];
            const float bv2 = b1[ghid + 2], bv3 = b1[ghid + 3];
            const int c16 = hh >> 3;
#pragma unroll
            for (int nt = 0; nt < 4; ++nt) {
                const int p = 16 * nt + ln;
                float v0 = acc1[mt][nt][0] + bv0; v0 = v0 > 0.f ? v0 : 0.f;
                float v1 = acc1[mt][nt][1] + bv1; v1 = v1 > 0.f ? v1 : 0.f;
                float v2 = acc1[mt][nt][2] + bv2; v2 = v2 > 0.f ? v2 : 0.f;
                float v3 = acc1[mt][nt][3] + bv3; v3 = v3 > 0.f ? v3 : 0.f;
                uint2 pk;
                pk.x = (unsigned int)f2bf(v0) | ((unsigned int)f2bf(v1) << 16);
                pk.y = (unsigned int)f2bf(v2) | ((unsigned int)f2bf(v3) << 16);
                ht2[(p * 32 + (c16 ^ sw)) * 2 + (q & 1)] = pk;
            }
        }
        __syncthreads();
        const unsigned short* b2b = W2 + hf * 32768 + w * 8192 + q * 128 + ln * 8;
#pragma unroll
        for (int ks = 0; ks < 8; ++ks) {
            bf16x8 b2f[2];
#pragma unroll
            for (int nt = 0; nt < 2; ++nt)
                b2f[nt] = *(const bf16x8*)(b2b + nt * 4096 + ks * 512);
#pragma unroll
            for (int mt = 0; mt < 4; ++mt) {
                bf16x8 af2 = *(const bf16x8*)&ht2[((16 * mt + ln) * 32 + ((4 * ks + q) ^ sw)) * 2];
#pragma unroll
                for (int nt = 0; nt < 2; ++nt)
                    acc2[mt][nt] = __builtin_amdgcn_mfma_f32_16x16x32_bf16(
                        af2, b2f[nt], acc2[mt][nt], 0, 0, 0);
            }
        }
        __syncthreads();
    }

    // epilogue2: +b2, BN, residual
    {
        const float* b2  = P.b2s[TF];
        const float* gam = P.gs[TF];
        const float* bet = P.bes[TF];
        const float* mean = P.ms[TF];
        const float* var  = P.vvs[TF];
#pragma unroll
        for (int nt = 0; nt < 2; ++nt) {
            const int c = 32 * w + 16 * nt + ln;
            const float bia = b2[c];
            const float sc  = gam[c] * rsqrtf(var[c] + EPS);
            const float bb  = bet[c];
            const float mu  = mean[c];
#pragma unroll
            for (int mt = 0; mt < 4; ++mt) {
#pragma unroll
                for (int r = 0; r < 4; ++r) {
                    const int rl = 16 * mt + 4 * q + r;
                    const size_t o = (size_t)(p0 + rl) * 128 + c;
                    float v  = acc2[mt][nt][r] + bia;
                    float y  = (v - mu) * sc + bb;
                    float xn = xold[o] + y;
                    P.xf[o] = xn;
                    if constexpr (TV >= 0)
                        xt[(rl * 16 + ((c >> 3) ^ (rl & 7))) * 8 + (c & 7)] = f2bf(xn);
                }
            }
        }
    }

    // ---------------- VFR linear ----------------
    if constexpr (TV >= 0) {
        __syncthreads();
        const unsigned short* VT = P.VTP[TV];
        const float* vb = P.vbb[TV];
        const int wm  = (w >> 1) * 32;
        const int hfv = w & 1;
        floatx4 acc[2][4];
#pragma unroll
        for (int i = 0; i < 2; ++i)
#pragma unroll
            for (int j = 0; j < 4; ++j) acc[i][j] = zero;

        const unsigned short* bb2 = VT + hfv * 8192 + q * 128 + ln * 8;
#pragma unroll
        for (int ks = 0; ks < 4; ++ks) {
            bf16x8 bfr[4];
#pragma unroll
            for (int nt = 0; nt < 4; ++nt)
                bfr[nt] = *(const bf16x8*)(bb2 + nt * 2048 + ks * 512);
#pragma unroll
            for (int mt = 0; mt < 2; ++mt) {
                bf16x8 af = *(const bf16x8*)&xt[((wm + 16 * mt + ln) * 16 + ((4 * ks + q) ^ sw)) * 8];
#pragma unroll
                for (int nt = 0; nt < 4; ++nt)
                    acc[mt][nt] = __builtin_amdgcn_mfma_f32_16x16x32_bf16(
                        af, bfr[nt], acc[mt][nt], 0, 0, 0);
            }
        }
#pragma unroll
        for (int nt = 0; nt < 4; ++nt) {
            const int c = 64 * hfv + 16 * nt + ln;
            const float bia = vb[c];
#pragma unroll
            for (int mt = 0; mt < 2; ++mt) {
#pragma unroll
                for (int r = 0; r < 4; ++r) {
                    const int row = p0 + wm + 16 * mt + 4 * q + r;
                    VbOut[(size_t)row * 128 + c] = f2bf(acc[mt][nt][r] + bia);
                }
            }
        }
    }
}

// ---------------- launch ----------------
extern "C" void kernel_launch(void* const* d_in, const int* in_sizes, int n_in,
                              void* d_out, int out_size, void* d_ws, size_t ws_size,
                              hipStream_t stream)
{
    Params p;
    p.x_in = (const float*)d_in[0];
    p.knn  = (const int*)d_in[1];
    const float* w1  = (const float*)d_in[2];
    const float* b1  = (const float*)d_in[3];
    const float* w2  = (const float*)d_in[4];
    const float* b2  = (const float*)d_in[5];
    const float* g0  = (const float*)d_in[6];
    const float* be0 = (const float*)d_in[7];
    const float* m0p = (const float*)d_in[8];
    const float* v0p = (const float*)d_in[9];
    const float* vw  = (const float*)d_in[10];
    const float* vbp = (const float*)d_in[11];
    const float* vgp = (const float*)d_in[12];
    const float* vbe = (const float*)d_in[13];
    const float* vmp = (const float*)d_in[14];
    const float* vvp = (const float*)d_in[15];
    const float* fw1 = (const float*)d_in[16];
    const float* fb1 = (const float*)d_in[17];
    const float* fw2 = (const float*)d_in[18];
    const float* fb2 = (const float*)d_in[19];
    const float* fg  = (const float*)d_in[20];
    const float* fbe = (const float*)d_in[21];
    const float* fm  = (const float*)d_in[22];
    const float* fv  = (const float*)d_in[23];

    p.w1s[0] = w1;  p.w1s[1] = fw1; p.w1s[2] = fw1 + 65536;
    p.w2s[0] = w2;  p.w2s[1] = fw2; p.w2s[2] = fw2 + 65536;
    p.vws[0] = vw;  p.vws[1] = vw + 16384;
    p.b1s[0] = b1;  p.b1s[1] = fb1; p.b1s[2] = fb1 + 512;
    p.b2s[0] = b2;  p.b2s[1] = fb2; p.b2s[2] = fb2 + 128;
    p.gs[0]  = g0;  p.gs[1]  = fg;  p.gs[2]  = fg + 128;
    p.bes[0] = be0; p.bes[1] = fbe; p.bes[2] = fbe + 128;
    p.ms[0]  = m0p; p.ms[1]  = fm;  p.ms[2]  = fm + 128;
    p.vvs[0] = v0p; p.vvs[1] = fv;  p.vvs[2] = fv + 128;
    p.vbb[0] = vbp; p.vbb[1] = vbp + 128;
    p.vgg[0] = vgp; p.vgg[1] = vgp + 128;
    p.vbt[0] = vbe; p.vbt[1] = vbe + 128;
    p.vmm[0] = vmp; p.vmm[1] = vmp + 128;
    p.vva[0] = vvp; p.vva[1] = vvp + 128;

    char* ws = (char*)d_ws;
    unsigned short* Vb0 = (unsigned short*)ws;                          // 8 MiB
    unsigned short* Vb1 = (unsigned short*)(ws + (size_t)(8 << 20));    // 8 MiB
    unsigned short* u   = (unsigned short*)(ws + (size_t)(16 << 20));   // packed weights
    for (int i = 0; i < 3; ++i) p.W1P[i] = u + i * 65536;
    for (int i = 0; i < 3; ++i) p.W2P[i] = u + 196608 + i * 65536;
    for (int i = 0; i < 2; ++i) p.VTP[i] = u + 393216 + i * 16384;
    p.xf = (float*)d_out;

    pack_weights<<<dim3(512), 256, 0, stream>>>(p);
    stage<1, -1, 0, 0><<<dim3(512), 256, 0, stream>>>(p, p.x_in, nullptr, Vb0);
    stage<0,  0, 1, 1><<<dim3(512), 256, 0, stream>>>(p, p.xf, Vb0, Vb1);
    stage<0,  1, 2, -1><<<dim3(512), 256, 0, stream>>>(p, p.xf, Vb1, nullptr);
}

// Round 6
// 184.187 us; speedup vs baseline: 1.5682x; 1.2896x over previous
//
#include <hip/hip_runtime.h>
#include <hip/hip_bf16.h>
#include <stdint.h>

typedef __attribute__((ext_vector_type(8))) __bf16 bf16x8;
typedef __attribute__((ext_vector_type(4))) float floatx4;

#define EPS 1e-5f

__device__ __forceinline__ unsigned short f2bf(float f) {
    union { float f; unsigned int u; } x; x.f = f;
    unsigned int r = x.u + 0x7fffu + ((x.u >> 16) & 1u);
    return (unsigned short)(r >> 16);
}

__device__ __forceinline__ float bf2f(unsigned int u) {
    union { unsigned int u; float f; } x; x.u = u << 16; return x.f;
}

struct Params {
    const float* x_in;
    const int*   knn;
    const float* w1s[3];   // [128][512]
    const float* w2s[3];   // [512][128]
    const float* vws[2];   // [128][128]
    unsigned short* W1P[3];
    unsigned short* W2P[3];
    unsigned short* VTP[2];
    const float* b1s[3];
    const float* b2s[3];
    const float* gs[3];
    const float* bes[3];
    const float* ms[3];
    const float* vvs[3];
    const float* vbb[2];
    const float* vgg[2];
    const float* vbt[2];
    const float* vmm[2];
    const float* vva[2];
    float* xf;
};

// ---------------- pack weights fragment-major (bf16), coalesced reads ------
// W1P addr = hf*16384 + w*2048 + ks*512 + q*128 + ln*8 + j
//   holds W1[k=32ks+8q+j][h=128hf+16w+ln]        (src [128][512], idx=k*512+h)
// W2P addr = hf*16384 + w*2048 + ks*512 + q*128 + ln*8 + j
//   holds W2[h=128hf+32ks+8q+j][c=16w+ln]        (src [512][128], idx=h*128+c)
// VTP addr = w*2048 + ks*512 + q*128 + ln*8 + j
//   holds Wv[k=32ks+8q+j][c=16w+ln]              (src [128][128], idx=k*128+c)
__global__ __launch_bounds__(256) void pack_weights(Params P) {
    const int gtid = blockIdx.x * 256 + threadIdx.x;
    const int GT   = gridDim.x * 256;
#pragma unroll
    for (int t = 0; t < 3; ++t) {
        const float* s1 = P.w1s[t];
        unsigned short* d1 = P.W1P[t];
        for (int idx = gtid; idx < 65536; idx += GT) {
            int h = idx & 511, k = idx >> 9;
            int hf = h >> 7, w = (h >> 4) & 7, ln = h & 15;
            int ks = (k >> 5) & 3, q = (k >> 3) & 3, j = k & 7;
            d1[hf * 16384 + w * 2048 + ks * 512 + q * 128 + ln * 8 + j] = f2bf(s1[idx]);
        }
        const float* s2 = P.w2s[t];
        unsigned short* d2 = P.W2P[t];
        for (int idx = gtid; idx < 65536; idx += GT) {
            int c = idx & 127, h = idx >> 7;
            int hf = h >> 7, ks = (h >> 5) & 3, q = (h >> 3) & 3, j = h & 7;
            int w = c >> 4, ln = c & 15;
            d2[hf * 16384 + w * 2048 + ks * 512 + q * 128 + ln * 8 + j] = f2bf(s2[idx]);
        }
    }
#pragma unroll
    for (int t = 0; t < 2; ++t) {
        const float* sv = P.vws[t];
        unsigned short* dv = P.VTP[t];
        for (int idx = gtid; idx < 16384; idx += GT) {
            int c = idx & 127, k = idx >> 7;
            int ks = (k >> 5) & 3, q = (k >> 3) & 3, j = k & 7;
            int w = c >> 4, ln = c & 15;
            dv[w * 2048 + ks * 512 + q * 128 + ln * 8 + j] = f2bf(sv[idx]);
        }
    }
}

// ---------------- fused stage kernel (512 thr = 8 waves, 64 points) --------
// LDS 64 KB total: xt (bf16 x tile, 16K) + xf32 (fp32 post-edge x, 32K)
//                + ht2 (h tile, one 128-hid slice, 16K)
// Phases: [LOADX] x_in -> xf32+xt | [TE] edge: xf32,xt = xf + BN(edgemax)
//         FFN (hidden-split x4, acc2 accumulated across slices)
//         epilogue2: xf = xf32 + BN(ffn); xt=bf16 | [TV] VFR: VbOut
// XCD swizzle: bid = (phys&7)*64 + phys>>3  => XCD i works on batch i only.
template <int LOADX, int TE, int TF, int TV>
__global__ __launch_bounds__(512, 4)
void stage(Params P, const float* __restrict__ xold_g,
           const unsigned short* __restrict__ VbIn,
           unsigned short* __restrict__ VbOut)
{
    __shared__ __align__(16) unsigned short xt[8192];   // 16 KB
    __shared__ __align__(16) float xf32[8192];          // 32 KB
    __shared__ __align__(16) uint2 ht2[2048];           // 16 KB
    const int tid  = threadIdx.x;
    const int lane = tid & 63;
    const int w    = tid >> 6;       // wave 0..7
    const int q    = lane >> 4;
    const int ln   = lane & 15;
    const int sw   = ln & 7;
    const int phys = blockIdx.x;
    const int bid  = (phys & 7) * 64 + (phys >> 3);   // XCD-local batches
    const int p0   = bid << 6;
    const floatx4 zero = {0.f, 0.f, 0.f, 0.f};

    if constexpr (LOADX) {
        const int r = tid >> 3, seg = tid & 7;
        const float4* src = (const float4*)(xold_g + (size_t)(p0 + r) * 128 + seg * 16);
        float4* dstf = (float4*)&xf32[r * 128 + seg * 16];
#pragma unroll
        for (int i = 0; i < 2; ++i) {
            float4 a = src[2 * i];
            float4 b = src[2 * i + 1];
            dstf[2 * i]     = a;
            dstf[2 * i + 1] = b;
            int kq = seg * 2 + i;
            uint4 pk;
            pk.x = (unsigned int)f2bf(a.x) | ((unsigned int)f2bf(a.y) << 16);
            pk.y = (unsigned int)f2bf(a.z) | ((unsigned int)f2bf(a.w) << 16);
            pk.z = (unsigned int)f2bf(b.x) | ((unsigned int)f2bf(b.y) << 16);
            pk.w = (unsigned int)f2bf(b.z) | ((unsigned int)f2bf(b.w) << 16);
            *(uint4*)&xt[(r * 16 + (kq ^ (r & 7))) * 8] = pk;
        }
    }

    if constexpr (TE >= 0) {
        const int c0 = lane << 1;
        float2 gv = *(const float2*)(P.vgg[TE] + c0);
        float2 bv = *(const float2*)(P.vbt[TE] + c0);
        float2 mv = *(const float2*)(P.vmm[TE] + c0);
        float2 vv = *(const float2*)(P.vva[TE] + c0);
        const float sc0 = gv.x * rsqrtf(vv.x + EPS);
        const float sc1 = gv.y * rsqrtf(vv.y + EPS);
#pragma unroll
        for (int it = 0; it < 8; ++it) {
            const int pl = it * 8 + w;
            const int p  = p0 + pl;
            const int b  = p >> 12;
            const size_t rowoff = (size_t)p * 128 + c0;
            unsigned int su = *(const unsigned int*)(VbIn + rowoff);
            const int4* kp4 = (const int4*)(P.knn + (size_t)p * 16);
            int4 ka = kp4[0], kb = kp4[1], kc = kp4[2], kd = kp4[3];
            const unsigned short* vbase = VbIn + (((size_t)b << 12) << 7) + c0;
            float m0 = -3.4e38f, m1 = -3.4e38f;
            unsigned int u;
#define GATH(IDX) u = *(const unsigned int*)(vbase + ((size_t)(IDX) << 7)); \
            m0 = fmaxf(m0, bf2f(u & 0xffffu)); m1 = fmaxf(m1, bf2f(u >> 16));
            GATH(ka.x) GATH(ka.y) GATH(ka.z) GATH(ka.w)
            GATH(kb.x) GATH(kb.y) GATH(kb.z) GATH(kb.w)
            GATH(kc.x) GATH(kc.y) GATH(kc.z) GATH(kc.w)
            GATH(kd.x) GATH(kd.y) GATH(kd.z) GATH(kd.w)
#undef GATH
            float s0 = bf2f(su & 0xffffu), s1 = bf2f(su >> 16);
            float y0 = (m0 - s0 - mv.x) * sc0 + bv.x;
            float y1 = (m1 - s1 - mv.y) * sc1 + bv.y;
            float2 xv = *(const float2*)(xold_g + rowoff);
            float xn0 = xv.x + y0, xn1 = xv.y + y1;
            *(float2*)&xf32[pl * 128 + c0] = make_float2(xn0, xn1);
            unsigned int pk = (unsigned int)f2bf(xn0) | ((unsigned int)f2bf(xn1) << 16);
            ((unsigned int*)xt)[(pl * 16 + ((lane >> 2) ^ (pl & 7))) * 4 + (lane & 3)] = pk;
        }
    }
    __syncthreads();

    // ---------------- FFN, hidden-split x4 ----------------
    floatx4 acc2[4];
#pragma unroll
    for (int i = 0; i < 4; ++i) acc2[i] = zero;

    const unsigned short* W1 = P.W1P[TF];
    const unsigned short* W2 = P.W2P[TF];
    const float* b1 = P.b1s[TF];

#pragma unroll
    for (int hf = 0; hf < 4; ++hf) {
        // GEMM1: h^T slice (M=128 hid, N=64 pts, K=128); wave w: hid 16w..16w+15
        floatx4 acc1[4];
#pragma unroll
        for (int i = 0; i < 4; ++i) acc1[i] = zero;
        const unsigned short* a1 = W1 + hf * 16384 + w * 2048 + q * 128 + ln * 8;
#pragma unroll
        for (int ks = 0; ks < 4; ++ks) {
            bf16x8 af = *(const bf16x8*)(a1 + ks * 512);
#pragma unroll
            for (int nt = 0; nt < 4; ++nt) {
                bf16x8 bfr = *(const bf16x8*)&xt[((16 * nt + ln) * 16 + ((4 * ks + q) ^ sw)) * 8];
                acc1[nt] = __builtin_amdgcn_mfma_f32_16x16x32_bf16(af, bfr, acc1[nt], 0, 0, 0);
            }
        }
        // epilogue1: +b1, relu, pack 4 consecutive hid -> ht
        {
            const int hid0 = 16 * w + 4 * q;          // within this 128-slice
            const int ghid = 128 * hf + hid0;
            const float bv0 = b1[ghid + 0], bv1 = b1[ghid + 1];
            const float bv2 = b1[ghid + 2], bv3 = b1[ghid + 3];
            const int c16  = hid0 >> 3;
            const int half = q & 1;
#pragma unroll
            for (int nt = 0; nt < 4; ++nt) {
                const int pt = 16 * nt + ln;
                float v0 = acc1[nt][0] + bv0; v0 = v0 > 0.f ? v0 : 0.f;
                float v1 = acc1[nt][1] + bv1; v1 = v1 > 0.f ? v1 : 0.f;
                float v2 = acc1[nt][2] + bv2; v2 = v2 > 0.f ? v2 : 0.f;
                float v3 = acc1[nt][3] + bv3; v3 = v3 > 0.f ? v3 : 0.f;
                uint2 pk;
                pk.x = (unsigned int)f2bf(v0) | ((unsigned int)f2bf(v1) << 16);
                pk.y = (unsigned int)f2bf(v2) | ((unsigned int)f2bf(v3) << 16);
                ht2[(pt * 16 + (c16 ^ (pt & 7))) * 2 + half] = pk;
            }
        }
        __syncthreads();
        // GEMM2: y += h_slice @ W2_slice (M=64 pts, N=128 ch, K=128); wave w: ch 16w..
        const unsigned short* b2b = W2 + hf * 16384 + w * 2048 + q * 128 + ln * 8;
#pragma unroll
        for (int ks = 0; ks < 4; ++ks) {
            bf16x8 bw = *(const bf16x8*)(b2b + ks * 512);
#pragma unroll
            for (int mt = 0; mt < 4; ++mt) {
                bf16x8 ah = *(const bf16x8*)&ht2[((16 * mt + ln) * 16 + ((4 * ks + q) ^ sw)) * 2];
                acc2[mt] = __builtin_amdgcn_mfma_f32_16x16x32_bf16(ah, bw, acc2[mt], 0, 0, 0);
            }
        }
        __syncthreads();
    }

    // epilogue2: +b2, BN, residual (fp32 base from LDS), write xf (+xt)
    {
        const float* b2   = P.b2s[TF];
        const float* gam  = P.gs[TF];
        const float* bet  = P.bes[TF];
        const float* mean = P.ms[TF];
        const float* var  = P.vvs[TF];
        const int c = 16 * w + ln;
        const float bia = b2[c];
        const float sc  = gam[c] * rsqrtf(var[c] + EPS);
        const float bb  = bet[c];
        const float mu  = mean[c];
#pragma unroll
        for (int mt = 0; mt < 4; ++mt) {
#pragma unroll
            for (int r = 0; r < 4; ++r) {
                const int rl = 16 * mt + 4 * q + r;
                float v  = acc2[mt][r] + bia;
                float y  = (v - mu) * sc + bb;
                float xn = xf32[rl * 128 + c] + y;
                P.xf[(size_t)(p0 + rl) * 128 + c] = xn;
                if constexpr (TV >= 0)
                    xt[(rl * 16 + ((c >> 3) ^ (rl & 7))) * 8 + (c & 7)] = f2bf(xn);
            }
        }
    }

    // ---------------- VFR linear ----------------
    if constexpr (TV >= 0) {
        __syncthreads();
        const unsigned short* VT = P.VTP[TV];
        const float* vb = P.vbb[TV];
        floatx4 acc[4];
#pragma unroll
        for (int i = 0; i < 4; ++i) acc[i] = zero;
        const unsigned short* bb2 = VT + w * 2048 + q * 128 + ln * 8;
#pragma unroll
        for (int ks = 0; ks < 4; ++ks) {
            bf16x8 bw = *(const bf16x8*)(bb2 + ks * 512);
#pragma unroll
            for (int mt = 0; mt < 4; ++mt) {
                bf16x8 ax = *(const bf16x8*)&xt[((16 * mt + ln) * 16 + ((4 * ks + q) ^ sw)) * 8];
                acc[mt] = __builtin_amdgcn_mfma_f32_16x16x32_bf16(ax, bw, acc[mt], 0, 0, 0);
            }
        }
        const int c = 16 * w + ln;
        const float bia = vb[c];
#pragma unroll
        for (int mt = 0; mt < 4; ++mt)
#pragma unroll
            for (int r = 0; r < 4; ++r)
                VbOut[(size_t)(p0 + 16 * mt + 4 * q + r) * 128 + c] = f2bf(acc[mt][r] + bia);
    }
}

// ---------------- launch ----------------
extern "C" void kernel_launch(void* const* d_in, const int* in_sizes, int n_in,
                              void* d_out, int out_size, void* d_ws, size_t ws_size,
                              hipStream_t stream)
{
    Params p;
    p.x_in = (const float*)d_in[0];
    p.knn  = (const int*)d_in[1];
    const float* w1  = (const float*)d_in[2];
    const float* b1  = (const float*)d_in[3];
    const float* w2  = (const float*)d_in[4];
    const float* b2  = (const float*)d_in[5];
    const float* g0  = (const float*)d_in[6];
    const float* be0 = (const float*)d_in[7];
    const float* m0p = (const float*)d_in[8];
    const float* v0p = (const float*)d_in[9];
    const float* vw  = (const float*)d_in[10];
    const float* vbp = (const float*)d_in[11];
    const float* vgp = (const float*)d_in[12];
    const float* vbe = (const float*)d_in[13];
    const float* vmp = (const float*)d_in[14];
    const float* vvp = (const float*)d_in[15];
    const float* fw1 = (const float*)d_in[16];
    const float* fb1 = (const float*)d_in[17];
    const float* fw2 = (const float*)d_in[18];
    const float* fb2 = (const float*)d_in[19];
    const float* fg  = (const float*)d_in[20];
    const float* fbe = (const float*)d_in[21];
    const float* fm  = (const float*)d_in[22];
    const float* fv  = (const float*)d_in[23];

    p.w1s[0] = w1;  p.w1s[1] = fw1; p.w1s[2] = fw1 + 65536;
    p.w2s[0] = w2;  p.w2s[1] = fw2; p.w2s[2] = fw2 + 65536;
    p.vws[0] = vw;  p.vws[1] = vw + 16384;
    p.b1s[0] = b1;  p.b1s[1] = fb1; p.b1s[2] = fb1 + 512;
    p.b2s[0] = b2;  p.b2s[1] = fb2; p.b2s[2] = fb2 + 128;
    p.gs[0]  = g0;  p.gs[1]  = fg;  p.gs[2]  = fg + 128;
    p.bes[0] = be0; p.bes[1] = fbe; p.bes[2] = fbe + 128;
    p.ms[0]  = m0p; p.ms[1]  = fm;  p.ms[2]  = fm + 128;
    p.vvs[0] = v0p; p.vvs[1] = fv;  p.vvs[2] = fv + 128;
    p.vbb[0] = vbp; p.vbb[1] = vbp + 128;
    p.vgg[0] = vgp; p.vgg[1] = vgp + 128;
    p.vbt[0] = vbe; p.vbt[1] = vbe + 128;
    p.vmm[0] = vmp; p.vmm[1] = vmp + 128;
    p.vva[0] = vvp; p.vva[1] = vvp + 128;

    char* ws = (char*)d_ws;
    unsigned short* Vb0 = (unsigned short*)ws;                          // 8 MiB
    unsigned short* Vb1 = (unsigned short*)(ws + (size_t)(8 << 20));    // 8 MiB
    unsigned short* u   = (unsigned short*)(ws + (size_t)(16 << 20));   // packed weights
    for (int i = 0; i < 3; ++i) p.W1P[i] = u + i * 65536;
    for (int i = 0; i < 3; ++i) p.W2P[i] = u + 196608 + i * 65536;
    for (int i = 0; i < 2; ++i) p.VTP[i] = u + 393216 + i * 16384;
    p.xf = (float*)d_out;

    pack_weights<<<dim3(512), 256, 0, stream>>>(p);
    stage<1, -1, 0, 0><<<dim3(512), 512, 0, stream>>>(p, p.x_in, nullptr, Vb0);
    stage<0,  0, 1, 1><<<dim3(512), 512, 0, stream>>>(p, p.xf, Vb0, Vb1);
    stage<0,  1, 2, -1><<<dim3(512), 512, 0, stream>>>(p, p.xf, Vb1, nullptr);
}